// Round 6
// baseline (632.262 us; speedup 1.0000x reference)
//
#include <hip/hip_runtime.h>
#include <hip/hip_bf16.h>

#define H0 480
#define W0 640
#define H1 240
#define W1 320
#define H2 120
#define W2 160
#define H3 60
#define W3 80

// fp32 weight buffer offsets (in floats) inside d_ws  (transposed pointwise copies)
#define W_PW1T  0      // 5*32  [c*32+o]
#define W_PW2T  160    // 32*64 [c*64+o]
#define W_PW3T  2208   // 64*64 [c*64+o]
#define WBUF_BYTES 65536

#define F2_PB (64 * H2 * W2)   // 1,228,800
#define F3_PB (64 * H3 * W3)   //   307,200

// ---------------- K0: transpose pointwise weights ---------------------------
__global__ __launch_bounds__(256) void k_cvt(
    const float* __restrict__ pw1, const float* __restrict__ pw2,
    const float* __restrict__ pw3, float* __restrict__ wb)
{
    int t = threadIdx.x;
    for (int i = t; i < 160;  i += 256) { int o = i / 5,  c = i % 5;  wb[W_PW1T + c*32 + o] = pw1[i]; }
    for (int i = t; i < 2048; i += 256) { int o = i >> 5, c = i & 31; wb[W_PW2T + c*64 + o] = pw2[i]; }
    for (int i = t; i < 4096; i += 256) { int o = i >> 6, c = i & 63; wb[W_PW3T + c*64 + o] = pw3[i]; }
}

// ---------------- K12: fused stage1+stage2, channel-round LDS tiling ---------
// tile = 8x32 f2 px, 256 threads, 1 px/thread, acc[64].
// 8 rounds x 4 f1-channels; f1 tile (17x65, pad 66) per round in LDS (17.95 KB).
// flow-derived d[5] cached in registers across rounds (computed once).
#define T2H 8
#define T2W 32
#define F1R 17
#define F1C 65
#define F1CP 66
#define F1N (F1R*F1CP)   // 1122 floats per channel
#define A_IT 5           // ceil(17*65/256)

__global__ __launch_bounds__(256) void k_fuse12(
    const float* __restrict__ flow, const float* __restrict__ dw1,
    const float* __restrict__ b1, const float* __restrict__ dw2,
    const float* __restrict__ b2, const float* __restrict__ wb,
    float* __restrict__ out)
{
    __shared__ float s_f1[4 * F1N];   // 17,952 B

    int t = threadIdx.x;
    int tile = blockIdx.x;            // 0..74  (15 x 5)
    int b = blockIdx.y;
    int tx = tile % 5, ty = tile / 5;
    int th0 = ty * T2H, tw0 = tx * T2W;
    int h1base = 2*th0 - 1, w1base = 2*tw0 - 1;
    int lh2 = t >> 5, lw2 = t & 31;

    float acc[64];
    #pragma unroll
    for (int o = 0; o < 64; o++) acc[o] = b2[o];

    float dc[A_IT][5];   // cached dw1 outputs per step-A pixel

    for (int round = 0; round < 8; ++round) {
        if (round) __syncthreads();
        int ob = round * 4;

        // ---- step A: 4 f1 channels of the 17x65 tile into LDS ----
        #pragma unroll
        for (int it = 0; it < A_IT; ++it) {
            int li = it*256 + t;
            if (li < F1R*F1C) {
                int r = li / F1C, cc = li - r*F1C;
                float* sp = s_f1 + r*F1CP + cc;
                int h1 = h1base + r, w1 = w1base + cc;
                if (h1 < 0 || w1 < 0) {
                    sp[0] = 0.f; sp[F1N] = 0.f; sp[2*F1N] = 0.f; sp[3*F1N] = 0.f;
                } else {
                    if (round == 0) {
                        int ih0 = 2*h1 - 1, iw0 = 2*w1 - 1;
                        float mh[3] = { ih0 >= 0 ? 1.f : 0.f, 1.f, 1.f };
                        float mw[3] = { iw0 >= 0 ? 1.f : 0.f, 1.f, 1.f };
                        int ihx[3] = { ih0 < 0 ? 0 : ih0, ih0 + 1, ih0 + 2 };
                        int iwx[3] = { iw0 < 0 ? 0 : iw0, iw0 + 1, iw0 + 2 };
                        #pragma unroll
                        for (int c = 0; c < 2; c++) {
                            const float* base = flow + ((size_t)(b*2 + c)) * (H0*W0);
                            float a = 0.f;
                            #pragma unroll
                            for (int ky = 0; ky < 3; ky++) {
                                const float* rp = base + (size_t)ihx[ky] * W0;
                                #pragma unroll
                                for (int kx = 0; kx < 3; kx++)
                                    a = fmaf(dw1[c*9 + ky*3 + kx], (mh[ky]*mw[kx]) * rp[iwx[kx]], a);
                            }
                            dc[it][c] = a;
                        }
                        const float sy = 2.f / (H0 - 1), sx = 2.f / (W0 - 1);
                        float ax = 0.f, ay = 0.f, ar = 0.f;
                        #pragma unroll
                        for (int ky = 0; ky < 3; ky++) {
                            float yv = fmaf((float)(ih0 + ky), sy, -1.f);
                            #pragma unroll
                            for (int kx = 0; kx < 3; kx++) {
                                float xv = fmaf((float)(iw0 + kx), sx, -1.f);
                                float m = mh[ky] * mw[kx];
                                ax = fmaf(dw1[18 + ky*3 + kx], m * xv, ax);
                                ay = fmaf(dw1[27 + ky*3 + kx], m * yv, ay);
                                ar = fmaf(dw1[36 + ky*3 + kx], m * (xv*xv + yv*yv), ar);
                            }
                        }
                        dc[it][2] = ax; dc[it][3] = ay; dc[it][4] = ar;
                    }
                    // pw1 for this round's 4 output channels + ELU
                    float a0 = b1[ob+0], a1 = b1[ob+1], a2 = b1[ob+2], a3 = b1[ob+3];
                    #pragma unroll
                    for (int c = 0; c < 5; c++) {
                        float dv = dc[it][c];
                        const float* wr = wb + W_PW1T + c*32 + ob;   // wave-uniform
                        a0 = fmaf(wr[0], dv, a0);
                        a1 = fmaf(wr[1], dv, a1);
                        a2 = fmaf(wr[2], dv, a2);
                        a3 = fmaf(wr[3], dv, a3);
                    }
                    sp[0]     = a0 > 0.f ? a0 : (__expf(a0) - 1.f);
                    sp[F1N]   = a1 > 0.f ? a1 : (__expf(a1) - 1.f);
                    sp[2*F1N] = a2 > 0.f ? a2 : (__expf(a2) - 1.f);
                    sp[3*F1N] = a3 > 0.f ? a3 : (__expf(a3) - 1.f);
                }
            }
        }
        __syncthreads();

        // ---- step B: dw2 taps from LDS (float2, even-aligned), pw2 via s-loads
        const float* sfb = s_f1 + (2*lh2)*F1CP + 2*lw2;
        #pragma unroll
        for (int j = 0; j < 4; ++j) {
            int c = ob + j;
            const float* w9 = dw2 + c*9;                 // wave-uniform
            const float* sf = sfb + j*F1N;
            float dv = 0.f;
            #pragma unroll
            for (int ky = 0; ky < 3; ky++) {
                float2 v0 = *(const float2*)(sf + ky*F1CP);
                float2 v1 = *(const float2*)(sf + ky*F1CP + 2);
                dv = fmaf(w9[ky*3 + 0], v0.x, dv);
                dv = fmaf(w9[ky*3 + 1], v0.y, dv);
                dv = fmaf(w9[ky*3 + 2], v1.x, dv);
            }
            const float* wrow = wb + W_PW2T + c*64;      // wave-uniform
            #pragma unroll
            for (int o = 0; o < 64; o++) acc[o] = fmaf(wrow[o], dv, acc[o]);
        }
    }

    // ---- epilogue: ELU + store ----
    int oh = th0 + lh2, ow = tw0 + lw2;
    size_t obase = ((size_t)b * 64) * (H2*W2) + (size_t)oh*W2 + ow;
    #pragma unroll
    for (int o = 0; o < 64; o++) {
        float v = acc[o];
        out[obase + (size_t)o*(H2*W2)] = v > 0.f ? v : (__expf(v) - 1.f);
    }
}

// ---------------- K3: dwsep3 + ELU, LDS-tiled, channel rounds ----------------
// tile = 6x20 f3 px, 128 threads (120 active in step B), acc[64].
// 16 rounds x 4 f2-channels; f2 tile (13x41, pad 42) per round in LDS (8.7 KB).
#define T3H 6
#define T3W 20
#define F2R 13
#define F2C 41
#define F2CP 42
#define F2N (F2R*F2CP)   // 546
#define A3_IT 5          // ceil(546/128)

__global__ __launch_bounds__(128) void k_stage3(
    const float* __restrict__ in, const float* __restrict__ dw3,
    const float* __restrict__ b3, const float* __restrict__ wb,
    float* __restrict__ out)
{
    __shared__ float s_f2[4 * F2N];   // 8,736 B

    int t = threadIdx.x;
    int tile = blockIdx.x;            // 0..39 (10 x 4)
    int b = blockIdx.y;
    int tx = tile % 4, ty = tile / 4;
    int th0 = ty * T3H, tw0 = tx * T3W;
    int h2base = 2*th0 - 1, w2base = 2*tw0 - 1;
    int lh = t / 20, lw = t - lh*20;
    bool active = t < 120;

    float acc[64];
    #pragma unroll
    for (int o = 0; o < 64; o++) acc[o] = b3[o];

    const float* inb = in + (size_t)b * F2_PB;

    for (int round = 0; round < 16; ++round) {
        if (round) __syncthreads();
        int cb = round * 4;

        // ---- step A: stage 4 f2 channels of the 13x42 (padded) tile ----
        #pragma unroll
        for (int it = 0; it < A3_IT; ++it) {
            int li = it*128 + t;
            if (li < F2N) {
                int r = li / F2CP, cc = li - r*F2CP;
                int h2 = h2base + r, w2 = w2base + cc;
                float* sp = s_f2 + r*F2CP + cc;
                if (cc >= F2C || h2 < 0 || w2 < 0) {
                    sp[0] = 0.f; sp[F2N] = 0.f; sp[2*F2N] = 0.f; sp[3*F2N] = 0.f;
                } else {
                    const float* g = inb + (size_t)h2*W2 + w2;
                    sp[0]     = g[(size_t)(cb+0)*(H2*W2)];
                    sp[F2N]   = g[(size_t)(cb+1)*(H2*W2)];
                    sp[2*F2N] = g[(size_t)(cb+2)*(H2*W2)];
                    sp[3*F2N] = g[(size_t)(cb+3)*(H2*W2)];
                }
            }
        }
        __syncthreads();

        // ---- step B ----
        if (active) {
            const float* sfb = s_f2 + (2*lh)*F2CP + 2*lw;
            #pragma unroll
            for (int j = 0; j < 4; ++j) {
                int c = cb + j;
                const float* w9 = dw3 + c*9;             // wave-uniform
                const float* sf = sfb + j*F2N;
                float dv = 0.f;
                #pragma unroll
                for (int ky = 0; ky < 3; ky++) {
                    float2 v0 = *(const float2*)(sf + ky*F2CP);
                    float2 v1 = *(const float2*)(sf + ky*F2CP + 2);
                    dv = fmaf(w9[ky*3 + 0], v0.x, dv);
                    dv = fmaf(w9[ky*3 + 1], v0.y, dv);
                    dv = fmaf(w9[ky*3 + 2], v1.x, dv);
                }
                const float* wrow = wb + W_PW3T + c*64;  // wave-uniform
                #pragma unroll
                for (int o = 0; o < 64; o++) acc[o] = fmaf(wrow[o], dv, acc[o]);
            }
        }
    }

    if (active) {
        int oh = th0 + lh, ow = tw0 + lw;
        size_t obase = ((size_t)b * 64) * (H3*W3) + (size_t)oh*W3 + ow;
        #pragma unroll
        for (int o = 0; o < 64; o++) {
            float v = acc[o];
            out[obase + (size_t)o*(H3*W3)] = v > 0.f ? v : (__expf(v) - 1.f);
        }
    }
}

// ---------------- K4: attention pool + MLP + GRU head -----------------------
__global__ __launch_bounds__(1024) void k_head(
    const float* __restrict__ f3,
    const float* __restrict__ attn_w, const float* __restrict__ attn_b,
    const float* __restrict__ mlp1_w, const float* __restrict__ mlp1_b,
    const float* __restrict__ mlp2_w, const float* __restrict__ mlp2_b,
    const float* __restrict__ w_ih, const float* __restrict__ b_ih,
    const float* __restrict__ b_hh,
    const float* __restrict__ fc_w, const float* __restrict__ fc_b,
    float* __restrict__ out)
{
    const int N  = H3 * W3;   // 4800
    const int N4 = N / 4;     // 1200
    __shared__ float s_w[H3 * W3];
    __shared__ float s_attn[64];
    __shared__ float s_redm[16];
    __shared__ float s_reds[16];
    __shared__ float s_inv[1];
    __shared__ float s_pooled[64];
    __shared__ float s_h1[32];
    __shared__ float s_om[3];
    __shared__ float s_h[32];

    int t = threadIdx.x, b = blockIdx.x;
    int lane = t & 63, wid = t >> 6;   // 16 waves
    if (t < 64) s_attn[t] = attn_w[t];
    __syncthreads();

    const float4* fb4 = (const float4*)(f3 + (size_t)b * F3_PB);
    float ab = attn_b[0];

    float lmax = -1e30f;
    for (int n4 = t; n4 < N4; n4 += 1024) {
        float4 l = make_float4(ab, ab, ab, ab);
        #pragma unroll 8
        for (int c = 0; c < 64; c++) {
            float4 v = fb4[c * N4 + n4];
            float a = s_attn[c];
            l.x = fmaf(a, v.x, l.x); l.y = fmaf(a, v.y, l.y);
            l.z = fmaf(a, v.z, l.z); l.w = fmaf(a, v.w, l.w);
        }
        ((float4*)s_w)[n4] = l;
        lmax = fmaxf(lmax, fmaxf(fmaxf(l.x, l.y), fmaxf(l.z, l.w)));
    }
    #pragma unroll
    for (int off = 32; off; off >>= 1) lmax = fmaxf(lmax, __shfl_down(lmax, off, 64));
    if (lane == 0) s_redm[wid] = lmax;
    __syncthreads();
    {
        float m = s_redm[0];
        #pragma unroll
        for (int i = 1; i < 16; i++) m = fmaxf(m, s_redm[i]);
        lmax = m;
    }

    float lsum = 0.f;
    for (int n = t; n < N; n += 1024) { float e = __expf(s_w[n] - lmax); s_w[n] = e; lsum += e; }
    #pragma unroll
    for (int off = 32; off; off >>= 1) lsum += __shfl_down(lsum, off, 64);
    if (lane == 0) s_reds[wid] = lsum;
    __syncthreads();
    if (t == 0) {
        float s = 0.f;
        #pragma unroll
        for (int i = 0; i < 16; i++) s += s_reds[i];
        s_inv[0] = 1.f / s;
    }
    __syncthreads();
    float invS = s_inv[0];

    const float4* sw4 = (const float4*)s_w;
    for (int c = wid; c < 64; c += 16) {
        float s = 0.f;
        for (int i = lane; i < N4; i += 64) {
            float4 v = fb4[c * N4 + i];
            float4 w = sw4[i];
            s = fmaf(v.x, w.x, s); s = fmaf(v.y, w.y, s);
            s = fmaf(v.z, w.z, s); s = fmaf(v.w, w.w, s);
        }
        #pragma unroll
        for (int off = 32; off; off >>= 1) s += __shfl_down(s, off, 64);
        if (lane == 0) s_pooled[c] = s * invS;
    }
    __syncthreads();

    if (t < 32) {
        float a = mlp1_b[t];
        #pragma unroll 8
        for (int c = 0; c < 64; c++) a = fmaf(mlp1_w[t*64 + c], s_pooled[c], a);
        s_h1[t] = a > 0.f ? a : (__expf(a) - 1.f);
    }
    __syncthreads();
    if (t < 3) {
        float a = mlp2_b[t];
        for (int j = 0; j < 32; j++) a = fmaf(mlp2_w[t*32 + j], s_h1[j], a);
        s_om[t] = a;
    }
    __syncthreads();
    if (t < 32) {
        float gr = b_ih[t], gz = b_ih[32 + t], gn = b_ih[64 + t];
        #pragma unroll
        for (int k = 0; k < 3; k++) {
            float ok = s_om[k];
            gr = fmaf(w_ih[t*3 + k],        ok, gr);
            gz = fmaf(w_ih[(32 + t)*3 + k], ok, gz);
            gn = fmaf(w_ih[(64 + t)*3 + k], ok, gn);
        }
        float hr = b_hh[t], hz = b_hh[32 + t], hn = b_hh[64 + t];
        float r = 1.f / (1.f + __expf(-(gr + hr)));
        float z = 1.f / (1.f + __expf(-(gz + hz)));
        float nn = tanhf(gn + r * hn);
        s_h[t] = (1.f - z) * nn;
    }
    __syncthreads();
    if (t < 3) {
        float dl = fc_b[t];
        for (int j = 0; j < 32; j++) dl = fmaf(fc_w[t*32 + j], s_h[j], dl);
        out[b*3 + t] = s_om[t] + dl;
    }
}

// ---------------- host ----------------
extern "C" void kernel_launch(void* const* d_in, const int* in_sizes, int n_in,
                              void* d_out, int out_size, void* d_ws, size_t ws_size,
                              hipStream_t stream)
{
    const float* flow = (const float*)d_in[0];
    float* wb = (float*)d_ws;

    // layout: [wbuf][f2 all 32 batches][f3 all 32 batches] = 196.7 MB (ws >= 275 MB)
    float* f2 = (float*)((char*)d_ws + WBUF_BYTES);
    float* f3 = f2 + (size_t)32 * F2_PB;

    k_cvt<<<1, 256, 0, stream>>>(
        (const float*)d_in[2], (const float*)d_in[5], (const float*)d_in[8], wb);

    // fused stage1+stage2: 75 tiles (15x5) x 32 batches
    k_fuse12<<<dim3(75, 32), 256, 0, stream>>>(
        flow, (const float*)d_in[1], (const float*)d_in[3],
        (const float*)d_in[4], (const float*)d_in[6], wb, f2);

    // stage3: 40 tiles (10x4) x 32 batches
    k_stage3<<<dim3(40, 32), 128, 0, stream>>>(
        f2, (const float*)d_in[7], (const float*)d_in[9], wb, f3);

    k_head<<<32, 1024, 0, stream>>>(f3,
        (const float*)d_in[10], (const float*)d_in[11],
        (const float*)d_in[12], (const float*)d_in[13],
        (const float*)d_in[14], (const float*)d_in[15],
        (const float*)d_in[16], (const float*)d_in[18],
        (const float*)d_in[19], (const float*)d_in[20],
        (const float*)d_in[21], (float*)d_out);
}

// Round 7
// 504.353 us; speedup vs baseline: 1.2536x; 1.2536x over previous
//
#include <hip/hip_runtime.h>
#include <hip/hip_bf16.h>

#define H0 480
#define W0 640
#define H1 240
#define W1 320
#define H2 120
#define W2 160
#define H3 60
#define W3 80

// fp32 weight buffer offsets (in floats) inside d_ws  (transposed pointwise copies)
#define W_PW1T  0      // 5*32  [c*32+o]
#define W_PW2T  160    // 32*64 [c*64+o]
#define W_PW3T  2208   // 64*64 [c*64+o]
#define WBUF_BYTES 65536

#define F2_PB (64 * H2 * W2)   // 1,228,800
#define F3_PB (64 * H3 * W3)   //   307,200

// ---------------- K0: transpose pointwise weights ---------------------------
__global__ __launch_bounds__(256) void k_cvt(
    const float* __restrict__ pw1, const float* __restrict__ pw2,
    const float* __restrict__ pw3, float* __restrict__ wb)
{
    int t = threadIdx.x;
    for (int i = t; i < 160;  i += 256) { int o = i / 5,  c = i % 5;  wb[W_PW1T + c*32 + o] = pw1[i]; }
    for (int i = t; i < 2048; i += 256) { int o = i >> 5, c = i & 31; wb[W_PW2T + c*64 + o] = pw2[i]; }
    for (int i = t; i < 4096; i += 256) { int o = i >> 6, c = i & 63; wb[W_PW3T + c*64 + o] = pw3[i]; }
}

// ---------------- K12: fused stage1+stage2 ----------------------------------
// f2 tile 8x32 = 256 px; 512 threads = 2 oc-halves per px (wave-aligned).
// d[5] (dw1 outputs) cached in LDS once; 8 rounds x 4 f1-channels staged as
// float4/px in even/odd-column arrays -> step-B taps are conflict-free b128.
#define FT_H 8
#define FT_W 32
#define FH_R 17            // f1 halo rows
#define FH_C 65            // f1 halo cols
#define FH_N (FH_R*FH_C)   // 1105
#define FQP  34            // quad pitch (evens 33, odds 32)

__global__ __launch_bounds__(512, 4) void k_fuse12(
    const float* __restrict__ flow, const float* __restrict__ dw1,
    const float* __restrict__ b1, const float* __restrict__ dw2,
    const float* __restrict__ b2, const float* __restrict__ wb,
    float* __restrict__ out)
{
    __shared__ float4 s_e[FH_R * FQP];   // 9,248 B
    __shared__ float4 s_o[FH_R * FQP];   // 9,248 B
    __shared__ float  s_d[FH_N * 5];     // 22,100 B

    int t = threadIdx.x;
    int tile = blockIdx.x;               // 0..74 (15 rows x 5 cols)
    int b = blockIdx.y;
    int tx = tile % 5, ty = tile / 5;
    int th0 = ty * FT_H, tw0 = tx * FT_W;
    int h1base = 2*th0 - 1, w1base = 2*tw0 - 1;
    int px = t & 255, half = t >> 8;     // wave-aligned half
    int lh2 = px >> 5, lw2 = px & 31;

    // ---- A0: dw1 + coords outputs d[5] for the 17x65 f1 halo -> LDS --------
    #pragma unroll
    for (int it = 0; it < 3; ++it) {
        int li = it*512 + t;
        if (li < FH_N) {
            int r = li / FH_C, cc = li - r*FH_C;
            int h1 = h1base + r, w1 = w1base + cc;
            if (h1 >= 0 && w1 >= 0) {
                int ih0 = 2*h1 - 1, iw0 = 2*w1 - 1;
                float mh[3] = { ih0 >= 0 ? 1.f : 0.f, 1.f, 1.f };
                float mw[3] = { iw0 >= 0 ? 1.f : 0.f, 1.f, 1.f };
                int ihx[3] = { ih0 < 0 ? 0 : ih0, ih0 + 1, ih0 + 2 };
                int iwx[3] = { iw0 < 0 ? 0 : iw0, iw0 + 1, iw0 + 2 };
                #pragma unroll
                for (int c = 0; c < 2; c++) {
                    const float* base = flow + ((size_t)(b*2 + c)) * (H0*W0);
                    float a = 0.f;
                    #pragma unroll
                    for (int ky = 0; ky < 3; ky++) {
                        const float* rp = base + (size_t)ihx[ky] * W0;
                        #pragma unroll
                        for (int kx = 0; kx < 3; kx++)
                            a = fmaf(dw1[c*9 + ky*3 + kx], (mh[ky]*mw[kx]) * rp[iwx[kx]], a);
                    }
                    s_d[li*5 + c] = a;
                }
                const float sy = 2.f / (H0 - 1), sx = 2.f / (W0 - 1);
                float ax = 0.f, ay = 0.f, ar = 0.f;
                #pragma unroll
                for (int ky = 0; ky < 3; ky++) {
                    float yv = fmaf((float)(ih0 + ky), sy, -1.f);
                    #pragma unroll
                    for (int kx = 0; kx < 3; kx++) {
                        float xv = fmaf((float)(iw0 + kx), sx, -1.f);
                        float m = mh[ky] * mw[kx];
                        ax = fmaf(dw1[18 + ky*3 + kx], m * xv, ax);
                        ay = fmaf(dw1[27 + ky*3 + kx], m * yv, ay);
                        ar = fmaf(dw1[36 + ky*3 + kx], m * (xv*xv + yv*yv), ar);
                    }
                }
                s_d[li*5 + 2] = ax; s_d[li*5 + 3] = ay; s_d[li*5 + 4] = ar;
            }
        }
    }
    __syncthreads();

    float acc[32];
    #pragma unroll
    for (int o = 0; o < 32; o++) acc[o] = b2[half*32 + o];

    for (int round = 0; round < 8; ++round) {
        if (round) __syncthreads();      // protect quad arrays from prev step B
        int ob = round * 4;

        // ---- stage 4 f1 channels (pw1 + ELU from cached d) ----
        #pragma unroll
        for (int it = 0; it < 3; ++it) {
            int li = it*512 + t;
            if (li < FH_N) {
                int r = li / FH_C, cc = li - r*FH_C;
                int h1 = h1base + r, w1 = w1base + cc;
                float4 q;
                if (h1 < 0 || w1 < 0) {
                    q = make_float4(0.f, 0.f, 0.f, 0.f);
                } else {
                    float d0 = s_d[li*5+0], d1 = s_d[li*5+1], d2 = s_d[li*5+2],
                          d3 = s_d[li*5+3], d4 = s_d[li*5+4];
                    float a0 = b1[ob+0], a1 = b1[ob+1], a2 = b1[ob+2], a3 = b1[ob+3];
                    const float* w0 = wb + W_PW1T + ob;   // [c*32 + o], uniform
                    a0 = fmaf(w0[0*32+0], d0, a0); a1 = fmaf(w0[0*32+1], d0, a1);
                    a2 = fmaf(w0[0*32+2], d0, a2); a3 = fmaf(w0[0*32+3], d0, a3);
                    a0 = fmaf(w0[1*32+0], d1, a0); a1 = fmaf(w0[1*32+1], d1, a1);
                    a2 = fmaf(w0[1*32+2], d1, a2); a3 = fmaf(w0[1*32+3], d1, a3);
                    a0 = fmaf(w0[2*32+0], d2, a0); a1 = fmaf(w0[2*32+1], d2, a1);
                    a2 = fmaf(w0[2*32+2], d2, a2); a3 = fmaf(w0[2*32+3], d2, a3);
                    a0 = fmaf(w0[3*32+0], d3, a0); a1 = fmaf(w0[3*32+1], d3, a1);
                    a2 = fmaf(w0[3*32+2], d3, a2); a3 = fmaf(w0[3*32+3], d3, a3);
                    a0 = fmaf(w0[4*32+0], d4, a0); a1 = fmaf(w0[4*32+1], d4, a1);
                    a2 = fmaf(w0[4*32+2], d4, a2); a3 = fmaf(w0[4*32+3], d4, a3);
                    q.x = a0 > 0.f ? a0 : (__expf(a0) - 1.f);
                    q.y = a1 > 0.f ? a1 : (__expf(a1) - 1.f);
                    q.z = a2 > 0.f ? a2 : (__expf(a2) - 1.f);
                    q.w = a3 > 0.f ? a3 : (__expf(a3) - 1.f);
                }
                float4* dst = (cc & 1) ? &s_o[r*FQP + (cc >> 1)] : &s_e[r*FQP + (cc >> 1)];
                *dst = q;
            }
        }
        __syncthreads();

        // ---- step B: dw2 (9 b128 taps) + pw2 (s-loaded weights) ----
        const float* wd = dw2 + ob*9;    // uniform
        float dv0 = 0.f, dv1 = 0.f, dv2 = 0.f, dv3 = 0.f;
        #pragma unroll
        for (int ky = 0; ky < 3; ky++) {
            int ro = (2*lh2 + ky) * FQP;
            float4 e0 = s_e[ro + lw2];
            float4 o0 = s_o[ro + lw2];
            float4 e1 = s_e[ro + lw2 + 1];
            dv0 = fmaf(wd[0*9+ky*3+0], e0.x, dv0); dv0 = fmaf(wd[0*9+ky*3+1], o0.x, dv0); dv0 = fmaf(wd[0*9+ky*3+2], e1.x, dv0);
            dv1 = fmaf(wd[1*9+ky*3+0], e0.y, dv1); dv1 = fmaf(wd[1*9+ky*3+1], o0.y, dv1); dv1 = fmaf(wd[1*9+ky*3+2], e1.y, dv1);
            dv2 = fmaf(wd[2*9+ky*3+0], e0.z, dv2); dv2 = fmaf(wd[2*9+ky*3+1], o0.z, dv2); dv2 = fmaf(wd[2*9+ky*3+2], e1.z, dv2);
            dv3 = fmaf(wd[3*9+ky*3+0], e0.w, dv3); dv3 = fmaf(wd[3*9+ky*3+1], o0.w, dv3); dv3 = fmaf(wd[3*9+ky*3+2], e1.w, dv3);
        }
        const float* wr0 = wb + W_PW2T + (ob+0)*64 + half*32;
        const float* wr1 = wb + W_PW2T + (ob+1)*64 + half*32;
        const float* wr2 = wb + W_PW2T + (ob+2)*64 + half*32;
        const float* wr3 = wb + W_PW2T + (ob+3)*64 + half*32;
        #pragma unroll
        for (int o = 0; o < 32; o++) {
            float a = acc[o];
            a = fmaf(wr0[o], dv0, a);
            a = fmaf(wr1[o], dv1, a);
            a = fmaf(wr2[o], dv2, a);
            a = fmaf(wr3[o], dv3, a);
            acc[o] = a;
        }
    }

    // ---- epilogue ----
    int oh = th0 + lh2, ow = tw0 + lw2;
    size_t obase = ((size_t)b*64 + half*32) * (H2*W2) + (size_t)oh*W2 + ow;
    #pragma unroll
    for (int o = 0; o < 32; o++) {
        float v = acc[o];
        out[obase + (size_t)o*(H2*W2)] = v > 0.f ? v : (__expf(v) - 1.f);
    }
}

// ---------------- K3: dwsep3 + ELU, same structure ---------------------------
// f3 tile 4x16 = 64 px; 128 threads = 2 oc-halves (wave-aligned).
// 16 rounds x 4 f2-channels staged as float4/px (even/odd arrays).
#define T3H 4
#define T3W 16
#define H3R 9              // f2 halo rows
#define H3C 33             // f2 halo cols
#define H3N (H3R*H3C)      // 297
#define QP3 18             // quad pitch (evens 17, odds 16)

__global__ __launch_bounds__(128, 4) void k_stage3(
    const float* __restrict__ in, const float* __restrict__ dw3,
    const float* __restrict__ b3, const float* __restrict__ wb,
    float* __restrict__ out)
{
    __shared__ float4 s_e[H3R * QP3];   // 2,592 B
    __shared__ float4 s_o[H3R * QP3];   // 2,592 B

    int t = threadIdx.x;
    int tile = blockIdx.x;              // 0..74 (15 rows x 5 cols)
    int b = blockIdx.y;
    int tx = tile % 5, ty = tile / 5;
    int th0 = ty * T3H, tw0 = tx * T3W;
    int h2base = 2*th0 - 1, w2base = 2*tw0 - 1;
    int px = t & 63, half = t >> 6;     // wave-aligned half
    int lh = px >> 4, lw = px & 15;

    float acc[32];
    #pragma unroll
    for (int o = 0; o < 32; o++) acc[o] = b3[half*32 + o];

    const float* inb = in + (size_t)b * F2_PB;

    for (int round = 0; round < 16; ++round) {
        if (round) __syncthreads();
        int cb = round * 4;

        // ---- stage 4 f2 channels of the 9x33 halo ----
        #pragma unroll
        for (int it = 0; it < 3; ++it) {
            int li = it*128 + t;
            if (li < H3N) {
                int r = li / H3C, cc = li - r*H3C;
                int h2 = h2base + r, w2 = w2base + cc;
                float4 q;
                if (h2 < 0 || w2 < 0) {
                    q = make_float4(0.f, 0.f, 0.f, 0.f);
                } else {
                    const float* g = inb + (size_t)h2*W2 + w2;
                    q.x = g[(size_t)(cb+0)*(H2*W2)];
                    q.y = g[(size_t)(cb+1)*(H2*W2)];
                    q.z = g[(size_t)(cb+2)*(H2*W2)];
                    q.w = g[(size_t)(cb+3)*(H2*W2)];
                }
                float4* dst = (cc & 1) ? &s_o[r*QP3 + (cc >> 1)] : &s_e[r*QP3 + (cc >> 1)];
                *dst = q;
            }
        }
        __syncthreads();

        // ---- step B ----
        const float* wd = dw3 + cb*9;   // uniform
        float dv0 = 0.f, dv1 = 0.f, dv2 = 0.f, dv3 = 0.f;
        #pragma unroll
        for (int ky = 0; ky < 3; ky++) {
            int ro = (2*lh + ky) * QP3;
            float4 e0 = s_e[ro + lw];
            float4 o0 = s_o[ro + lw];
            float4 e1 = s_e[ro + lw + 1];
            dv0 = fmaf(wd[0*9+ky*3+0], e0.x, dv0); dv0 = fmaf(wd[0*9+ky*3+1], o0.x, dv0); dv0 = fmaf(wd[0*9+ky*3+2], e1.x, dv0);
            dv1 = fmaf(wd[1*9+ky*3+0], e0.y, dv1); dv1 = fmaf(wd[1*9+ky*3+1], o0.y, dv1); dv1 = fmaf(wd[1*9+ky*3+2], e1.y, dv1);
            dv2 = fmaf(wd[2*9+ky*3+0], e0.z, dv2); dv2 = fmaf(wd[2*9+ky*3+1], o0.z, dv2); dv2 = fmaf(wd[2*9+ky*3+2], e1.z, dv2);
            dv3 = fmaf(wd[3*9+ky*3+0], e0.w, dv3); dv3 = fmaf(wd[3*9+ky*3+1], o0.w, dv3); dv3 = fmaf(wd[3*9+ky*3+2], e1.w, dv3);
        }
        const float* wr0 = wb + W_PW3T + (cb+0)*64 + half*32;
        const float* wr1 = wb + W_PW3T + (cb+1)*64 + half*32;
        const float* wr2 = wb + W_PW3T + (cb+2)*64 + half*32;
        const float* wr3 = wb + W_PW3T + (cb+3)*64 + half*32;
        #pragma unroll
        for (int o = 0; o < 32; o++) {
            float a = acc[o];
            a = fmaf(wr0[o], dv0, a);
            a = fmaf(wr1[o], dv1, a);
            a = fmaf(wr2[o], dv2, a);
            a = fmaf(wr3[o], dv3, a);
            acc[o] = a;
        }
    }

    int oh = th0 + lh, ow = tw0 + lw;
    size_t obase = ((size_t)b*64 + half*32) * (H3*W3) + (size_t)oh*W3 + ow;
    #pragma unroll
    for (int o = 0; o < 32; o++) {
        float v = acc[o];
        out[obase + (size_t)o*(H3*W3)] = v > 0.f ? v : (__expf(v) - 1.f);
    }
}

// ---------------- K4: attention pool + MLP + GRU head -----------------------
__global__ __launch_bounds__(1024) void k_head(
    const float* __restrict__ f3,
    const float* __restrict__ attn_w, const float* __restrict__ attn_b,
    const float* __restrict__ mlp1_w, const float* __restrict__ mlp1_b,
    const float* __restrict__ mlp2_w, const float* __restrict__ mlp2_b,
    const float* __restrict__ w_ih, const float* __restrict__ b_ih,
    const float* __restrict__ b_hh,
    const float* __restrict__ fc_w, const float* __restrict__ fc_b,
    float* __restrict__ out)
{
    const int N  = H3 * W3;   // 4800
    const int N4 = N / 4;     // 1200
    __shared__ float s_w[H3 * W3];
    __shared__ float s_attn[64];
    __shared__ float s_redm[16];
    __shared__ float s_reds[16];
    __shared__ float s_inv[1];
    __shared__ float s_pooled[64];
    __shared__ float s_h1[32];
    __shared__ float s_om[3];
    __shared__ float s_h[32];

    int t = threadIdx.x, b = blockIdx.x;
    int lane = t & 63, wid = t >> 6;   // 16 waves
    if (t < 64) s_attn[t] = attn_w[t];
    __syncthreads();

    const float4* fb4 = (const float4*)(f3 + (size_t)b * F3_PB);
    float ab = attn_b[0];

    float lmax = -1e30f;
    for (int n4 = t; n4 < N4; n4 += 1024) {
        float4 l = make_float4(ab, ab, ab, ab);
        #pragma unroll 8
        for (int c = 0; c < 64; c++) {
            float4 v = fb4[c * N4 + n4];
            float a = s_attn[c];
            l.x = fmaf(a, v.x, l.x); l.y = fmaf(a, v.y, l.y);
            l.z = fmaf(a, v.z, l.z); l.w = fmaf(a, v.w, l.w);
        }
        ((float4*)s_w)[n4] = l;
        lmax = fmaxf(lmax, fmaxf(fmaxf(l.x, l.y), fmaxf(l.z, l.w)));
    }
    #pragma unroll
    for (int off = 32; off; off >>= 1) lmax = fmaxf(lmax, __shfl_down(lmax, off, 64));
    if (lane == 0) s_redm[wid] = lmax;
    __syncthreads();
    {
        float m = s_redm[0];
        #pragma unroll
        for (int i = 1; i < 16; i++) m = fmaxf(m, s_redm[i]);
        lmax = m;
    }

    float lsum = 0.f;
    for (int n = t; n < N; n += 1024) { float e = __expf(s_w[n] - lmax); s_w[n] = e; lsum += e; }
    #pragma unroll
    for (int off = 32; off; off >>= 1) lsum += __shfl_down(lsum, off, 64);
    if (lane == 0) s_reds[wid] = lsum;
    __syncthreads();
    if (t == 0) {
        float s = 0.f;
        #pragma unroll
        for (int i = 0; i < 16; i++) s += s_reds[i];
        s_inv[0] = 1.f / s;
    }
    __syncthreads();
    float invS = s_inv[0];

    const float4* sw4 = (const float4*)s_w;
    for (int c = wid; c < 64; c += 16) {
        float s = 0.f;
        for (int i = lane; i < N4; i += 64) {
            float4 v = fb4[c * N4 + i];
            float4 w = sw4[i];
            s = fmaf(v.x, w.x, s); s = fmaf(v.y, w.y, s);
            s = fmaf(v.z, w.z, s); s = fmaf(v.w, w.w, s);
        }
        #pragma unroll
        for (int off = 32; off; off >>= 1) s += __shfl_down(s, off, 64);
        if (lane == 0) s_pooled[c] = s * invS;
    }
    __syncthreads();

    if (t < 32) {
        float a = mlp1_b[t];
        #pragma unroll 8
        for (int c = 0; c < 64; c++) a = fmaf(mlp1_w[t*64 + c], s_pooled[c], a);
        s_h1[t] = a > 0.f ? a : (__expf(a) - 1.f);
    }
    __syncthreads();
    if (t < 3) {
        float a = mlp2_b[t];
        for (int j = 0; j < 32; j++) a = fmaf(mlp2_w[t*32 + j], s_h1[j], a);
        s_om[t] = a;
    }
    __syncthreads();
    if (t < 32) {
        float gr = b_ih[t], gz = b_ih[32 + t], gn = b_ih[64 + t];
        #pragma unroll
        for (int k = 0; k < 3; k++) {
            float ok = s_om[k];
            gr = fmaf(w_ih[t*3 + k],        ok, gr);
            gz = fmaf(w_ih[(32 + t)*3 + k], ok, gz);
            gn = fmaf(w_ih[(64 + t)*3 + k], ok, gn);
        }
        float hr = b_hh[t], hz = b_hh[32 + t], hn = b_hh[64 + t];
        float r = 1.f / (1.f + __expf(-(gr + hr)));
        float z = 1.f / (1.f + __expf(-(gz + hz)));
        float nn = tanhf(gn + r * hn);
        s_h[t] = (1.f - z) * nn;
    }
    __syncthreads();
    if (t < 3) {
        float dl = fc_b[t];
        for (int j = 0; j < 32; j++) dl = fmaf(fc_w[t*32 + j], s_h[j], dl);
        out[b*3 + t] = s_om[t] + dl;
    }
}

// ---------------- host ----------------
extern "C" void kernel_launch(void* const* d_in, const int* in_sizes, int n_in,
                              void* d_out, int out_size, void* d_ws, size_t ws_size,
                              hipStream_t stream)
{
    const float* flow = (const float*)d_in[0];
    float* wb = (float*)d_ws;

    // layout: [wbuf][f2 all 32 batches][f3 all 32 batches] = 196.7 MB (ws >= 275 MB)
    float* f2 = (float*)((char*)d_ws + WBUF_BYTES);
    float* f3 = f2 + (size_t)32 * F2_PB;

    k_cvt<<<1, 256, 0, stream>>>(
        (const float*)d_in[2], (const float*)d_in[5], (const float*)d_in[8], wb);

    // fused stage1+stage2: 75 tiles (15x5) x 32 batches, 512 threads
    k_fuse12<<<dim3(75, 32), 512, 0, stream>>>(
        flow, (const float*)d_in[1], (const float*)d_in[3],
        (const float*)d_in[4], (const float*)d_in[6], wb, f2);

    // stage3: 75 tiles (15x5) x 32 batches, 128 threads
    k_stage3<<<dim3(75, 32), 128, 0, stream>>>(
        f2, (const float*)d_in[7], (const float*)d_in[9], wb, f3);

    k_head<<<32, 1024, 0, stream>>>(f3,
        (const float*)d_in[10], (const float*)d_in[11],
        (const float*)d_in[12], (const float*)d_in[13],
        (const float*)d_in[14], (const float*)d_in[15],
        (const float*)d_in[16], (const float*)d_in[18],
        (const float*)d_in[19], (const float*)d_in[20],
        (const float*)d_in[21], (float*)d_out);
}

// Round 8
// 344.832 us; speedup vs baseline: 1.8335x; 1.4626x over previous
//
#include <hip/hip_runtime.h>
#include <hip/hip_bf16.h>

#define H0 480
#define W0 640
#define H1 240
#define W1 320
#define H2 120
#define W2 160
#define H3 60
#define W3 80

// fp32 weight buffer offsets (in floats) inside d_ws  (transposed pointwise copies)
#define W_PW1T  0      // 5*32  [cin*32+o]
#define W_PW2T  160    // 32*64 [cin*64+o]
#define W_PW3T  2208   // 64*64 [cin*64+o]
#define WBUF_BYTES 65536

#define F2_PB (64 * H2 * W2)   // 1,228,800
#define F3_PB (64 * H3 * W3)   //   307,200

// ---------------- K0: transpose pointwise weights ---------------------------
__global__ __launch_bounds__(256) void k_cvt(
    const float* __restrict__ pw1, const float* __restrict__ pw2,
    const float* __restrict__ pw3, float* __restrict__ wb)
{
    int t = threadIdx.x;
    for (int i = t; i < 160;  i += 256) { int o = i / 5,  c = i % 5;  wb[W_PW1T + c*32 + o] = pw1[i]; }
    for (int i = t; i < 2048; i += 256) { int o = i >> 5, c = i & 31; wb[W_PW2T + c*64 + o] = pw2[i]; }
    for (int i = t; i < 4096; i += 256) { int o = i >> 6, c = i & 63; wb[W_PW3T + c*64 + o] = pw3[i]; }
}

// ---------------- K12: fused stage1+stage2, register-direct (no LDS) ---------
// 1 thread per f2 pixel. d[9][5] = dw1+coord outputs for the 3x3 f1 window,
// then per f1-channel: pw1+ELU (9 taps) -> dw2 -> rank-1 pw2 update of acc[64].
// All weights wave-uniform (s_loads); flow taps rely on L1/L2.
__global__ __launch_bounds__(256, 3) void k_fuse12(
    const float* __restrict__ flow, const float* __restrict__ dw1,
    const float* __restrict__ b1, const float* __restrict__ dw2,
    const float* __restrict__ b2, const float* __restrict__ wb,
    float* __restrict__ out)
{
    int idx = blockIdx.x * 256 + threadIdx.x;     // 614,400 exact
    int ow = idx % W2; int tmp = idx / W2; int oh = tmp % H2; int b = tmp / H2;

    int fh0 = 2*oh - 1, fw0 = 2*ow - 1;
    const float sy = 2.f / (H0 - 1), sx = 2.f / (W0 - 1);

    float d[9][5];
    float vm[9];

    #pragma unroll
    for (int r = 0; r < 3; r++) {
        #pragma unroll
        for (int s = 0; s < 3; s++) {
            int p = r*3 + s;
            int fh = fh0 + r, fw = fw0 + s;
            vm[p] = (fh >= 0 && fw >= 0) ? 1.f : 0.f;   // f1 zero-pad mask
            int fhc = fh < 0 ? 0 : fh, fwc = fw < 0 ? 0 : fw;
            int ih0 = 2*fhc - 1, iw0 = 2*fwc - 1;
            float mh[3] = { ih0 >= 0 ? 1.f : 0.f, 1.f, 1.f };
            float mw[3] = { iw0 >= 0 ? 1.f : 0.f, 1.f, 1.f };
            int ihx[3] = { ih0 < 0 ? 0 : ih0, ih0 + 1, ih0 + 2 };
            int iwx[3] = { iw0 < 0 ? 0 : iw0, iw0 + 1, iw0 + 2 };

            #pragma unroll
            for (int c = 0; c < 2; c++) {
                const float* base = flow + ((size_t)(b*2 + c)) * (H0*W0);
                float a = 0.f;
                #pragma unroll
                for (int ky = 0; ky < 3; ky++) {
                    const float* rp = base + (size_t)ihx[ky] * W0;
                    #pragma unroll
                    for (int kx = 0; kx < 3; kx++)
                        a = fmaf(dw1[c*9 + ky*3 + kx], (mh[ky]*mw[kx]) * rp[iwx[kx]], a);
                }
                d[p][c] = a;
            }
            float ax = 0.f, ay = 0.f, ar = 0.f;
            #pragma unroll
            for (int ky = 0; ky < 3; ky++) {
                float yv = fmaf((float)(ih0 + ky), sy, -1.f);
                #pragma unroll
                for (int kx = 0; kx < 3; kx++) {
                    float xv = fmaf((float)(iw0 + kx), sx, -1.f);
                    float m = mh[ky] * mw[kx];
                    ax = fmaf(dw1[18 + ky*3 + kx], m * xv, ax);
                    ay = fmaf(dw1[27 + ky*3 + kx], m * yv, ay);
                    ar = fmaf(dw1[36 + ky*3 + kx], m * (xv*xv + yv*yv), ar);
                }
            }
            d[p][2] = ax; d[p][3] = ay; d[p][4] = ar;
        }
    }

    float acc[64];
    #pragma unroll
    for (int o = 0; o < 64; o++) acc[o] = b2[o];

    for (int c = 0; c < 32; c++) {
        // pw1 column c (uniform s_loads)
        const float* w1 = wb + W_PW1T + c;
        float w10 = w1[0], w11 = w1[32], w12 = w1[64], w13 = w1[96], w14 = w1[128];
        float bc = b1[c];
        const float* w9 = dw2 + c*9;               // uniform
        float dv = 0.f;
        #pragma unroll
        for (int p = 0; p < 9; p++) {
            float v = bc;
            v = fmaf(w10, d[p][0], v);
            v = fmaf(w11, d[p][1], v);
            v = fmaf(w12, d[p][2], v);
            v = fmaf(w13, d[p][3], v);
            v = fmaf(w14, d[p][4], v);
            float f1v = v > 0.f ? v : (__expf(v) - 1.f);
            dv = fmaf(w9[p], f1v * vm[p], dv);
        }
        const float* wr = wb + W_PW2T + c*64;      // uniform
        #pragma unroll
        for (int o = 0; o < 64; o++) acc[o] = fmaf(wr[o], dv, acc[o]);
    }

    size_t obase = ((size_t)b * 64) * (H2*W2) + (size_t)oh*W2 + ow;
    #pragma unroll
    for (int o = 0; o < 64; o++) {
        float v = acc[o];
        out[obase + (size_t)o*(H2*W2)] = v > 0.f ? v : (__expf(v) - 1.f);
    }
}

// ---------------- K3: dwsep3 + ELU, register-direct (no LDS) -----------------
// 1 thread per f3 pixel; per f2-channel: 9 global taps (L3-warm) -> dw3 ->
// rank-1 pw3 update of acc[64].
__global__ __launch_bounds__(256, 4) void k_stage3(
    const float* __restrict__ in, const float* __restrict__ dw3,
    const float* __restrict__ b3, const float* __restrict__ wb,
    float* __restrict__ out)
{
    int idx = blockIdx.x * 256 + threadIdx.x;     // 153,600 exact
    int ow = idx % W3; int tmp = idx / W3; int oh = tmp % H3; int b = tmp / H3;
    int ih0 = 2*oh - 1, iw0 = 2*ow - 1;
    float mh[3] = { ih0 >= 0 ? 1.f : 0.f, 1.f, 1.f };
    float mw[3] = { iw0 >= 0 ? 1.f : 0.f, 1.f, 1.f };
    int ihx[3] = { ih0 < 0 ? 0 : ih0, ih0 + 1, ih0 + 2 };
    int iwx[3] = { iw0 < 0 ? 0 : iw0, iw0 + 1, iw0 + 2 };
    float m9[9];
    int off[9];
    #pragma unroll
    for (int ky = 0; ky < 3; ky++)
        #pragma unroll
        for (int kx = 0; kx < 3; kx++) {
            m9[ky*3 + kx] = mh[ky] * mw[kx];
            off[ky*3 + kx] = ihx[ky]*W2 + iwx[kx];
        }

    float acc[64];
    #pragma unroll
    for (int o = 0; o < 64; o++) acc[o] = b3[o];

    const float* inb = in + (size_t)b * F2_PB;
    for (int c = 0; c < 64; c++) {
        const float* g = inb + (size_t)c * (H2*W2);
        const float* w9 = dw3 + c*9;               // uniform
        float dv = 0.f;
        #pragma unroll
        for (int p = 0; p < 9; p++)
            dv = fmaf(w9[p], m9[p] * g[off[p]], dv);
        const float* wr = wb + W_PW3T + c*64;      // uniform
        #pragma unroll
        for (int o = 0; o < 64; o++) acc[o] = fmaf(wr[o], dv, acc[o]);
    }

    size_t obase = ((size_t)b * 64) * (H3*W3) + (size_t)oh*W3 + ow;
    #pragma unroll
    for (int o = 0; o < 64; o++) {
        float v = acc[o];
        out[obase + (size_t)o*(H3*W3)] = v > 0.f ? v : (__expf(v) - 1.f);
    }
}

// ---------------- K4: attention pool + MLP + GRU head -----------------------
__global__ __launch_bounds__(1024) void k_head(
    const float* __restrict__ f3,
    const float* __restrict__ attn_w, const float* __restrict__ attn_b,
    const float* __restrict__ mlp1_w, const float* __restrict__ mlp1_b,
    const float* __restrict__ mlp2_w, const float* __restrict__ mlp2_b,
    const float* __restrict__ w_ih, const float* __restrict__ b_ih,
    const float* __restrict__ b_hh,
    const float* __restrict__ fc_w, const float* __restrict__ fc_b,
    float* __restrict__ out)
{
    const int N  = H3 * W3;   // 4800
    const int N4 = N / 4;     // 1200
    __shared__ float s_w[H3 * W3];
    __shared__ float s_attn[64];
    __shared__ float s_redm[16];
    __shared__ float s_reds[16];
    __shared__ float s_inv[1];
    __shared__ float s_pooled[64];
    __shared__ float s_h1[32];
    __shared__ float s_om[3];
    __shared__ float s_h[32];

    int t = threadIdx.x, b = blockIdx.x;
    int lane = t & 63, wid = t >> 6;   // 16 waves
    if (t < 64) s_attn[t] = attn_w[t];
    __syncthreads();

    const float4* fb4 = (const float4*)(f3 + (size_t)b * F3_PB);
    float ab = attn_b[0];

    float lmax = -1e30f;
    for (int n4 = t; n4 < N4; n4 += 1024) {
        float4 l = make_float4(ab, ab, ab, ab);
        #pragma unroll 8
        for (int c = 0; c < 64; c++) {
            float4 v = fb4[c * N4 + n4];
            float a = s_attn[c];
            l.x = fmaf(a, v.x, l.x); l.y = fmaf(a, v.y, l.y);
            l.z = fmaf(a, v.z, l.z); l.w = fmaf(a, v.w, l.w);
        }
        ((float4*)s_w)[n4] = l;
        lmax = fmaxf(lmax, fmaxf(fmaxf(l.x, l.y), fmaxf(l.z, l.w)));
    }
    #pragma unroll
    for (int off = 32; off; off >>= 1) lmax = fmaxf(lmax, __shfl_down(lmax, off, 64));
    if (lane == 0) s_redm[wid] = lmax;
    __syncthreads();
    {
        float m = s_redm[0];
        #pragma unroll
        for (int i = 1; i < 16; i++) m = fmaxf(m, s_redm[i]);
        lmax = m;
    }

    float lsum = 0.f;
    for (int n = t; n < N; n += 1024) { float e = __expf(s_w[n] - lmax); s_w[n] = e; lsum += e; }
    #pragma unroll
    for (int off = 32; off; off >>= 1) lsum += __shfl_down(lsum, off, 64);
    if (lane == 0) s_reds[wid] = lsum;
    __syncthreads();
    if (t == 0) {
        float s = 0.f;
        #pragma unroll
        for (int i = 0; i < 16; i++) s += s_reds[i];
        s_inv[0] = 1.f / s;
    }
    __syncthreads();
    float invS = s_inv[0];

    const float4* sw4 = (const float4*)s_w;
    for (int c = wid; c < 64; c += 16) {
        float s = 0.f;
        for (int i = lane; i < N4; i += 64) {
            float4 v = fb4[c * N4 + i];
            float4 w = sw4[i];
            s = fmaf(v.x, w.x, s); s = fmaf(v.y, w.y, s);
            s = fmaf(v.z, w.z, s); s = fmaf(v.w, w.w, s);
        }
        #pragma unroll
        for (int off = 32; off; off >>= 1) s += __shfl_down(s, off, 64);
        if (lane == 0) s_pooled[c] = s * invS;
    }
    __syncthreads();

    if (t < 32) {
        float a = mlp1_b[t];
        #pragma unroll 8
        for (int c = 0; c < 64; c++) a = fmaf(mlp1_w[t*64 + c], s_pooled[c], a);
        s_h1[t] = a > 0.f ? a : (__expf(a) - 1.f);
    }
    __syncthreads();
    if (t < 3) {
        float a = mlp2_b[t];
        for (int j = 0; j < 32; j++) a = fmaf(mlp2_w[t*32 + j], s_h1[j], a);
        s_om[t] = a;
    }
    __syncthreads();
    if (t < 32) {
        float gr = b_ih[t], gz = b_ih[32 + t], gn = b_ih[64 + t];
        #pragma unroll
        for (int k = 0; k < 3; k++) {
            float ok = s_om[k];
            gr = fmaf(w_ih[t*3 + k],        ok, gr);
            gz = fmaf(w_ih[(32 + t)*3 + k], ok, gz);
            gn = fmaf(w_ih[(64 + t)*3 + k], ok, gn);
        }
        float hr = b_hh[t], hz = b_hh[32 + t], hn = b_hh[64 + t];
        float r = 1.f / (1.f + __expf(-(gr + hr)));
        float z = 1.f / (1.f + __expf(-(gz + hz)));
        float nn = tanhf(gn + r * hn);
        s_h[t] = (1.f - z) * nn;
    }
    __syncthreads();
    if (t < 3) {
        float dl = fc_b[t];
        for (int j = 0; j < 32; j++) dl = fmaf(fc_w[t*32 + j], s_h[j], dl);
        out[b*3 + t] = s_om[t] + dl;
    }
}

// ---------------- host ----------------
extern "C" void kernel_launch(void* const* d_in, const int* in_sizes, int n_in,
                              void* d_out, int out_size, void* d_ws, size_t ws_size,
                              hipStream_t stream)
{
    const float* flow = (const float*)d_in[0];
    float* wb = (float*)d_ws;

    // layout: [wbuf][f2 all 32 batches][f3 all 32 batches] = 196.7 MB (ws >= 275 MB)
    float* f2 = (float*)((char*)d_ws + WBUF_BYTES);
    float* f3 = f2 + (size_t)32 * F2_PB;

    k_cvt<<<1, 256, 0, stream>>>(
        (const float*)d_in[2], (const float*)d_in[5], (const float*)d_in[8], wb);

    // fused stage1+stage2: one thread per f2 pixel
    k_fuse12<<<(32*H2*W2)/256, 256, 0, stream>>>(
        flow, (const float*)d_in[1], (const float*)d_in[3],
        (const float*)d_in[4], (const float*)d_in[6], wb, f2);

    // stage3: one thread per f3 pixel
    k_stage3<<<(32*H3*W3)/256, 256, 0, stream>>>(
        f2, (const float*)d_in[7], (const float*)d_in[9], wb, f3);

    k_head<<<32, 1024, 0, stream>>>(f3,
        (const float*)d_in[10], (const float*)d_in[11],
        (const float*)d_in[12], (const float*)d_in[13],
        (const float*)d_in[14], (const float*)d_in[15],
        (const float*)d_in[16], (const float*)d_in[18],
        (const float*)d_in[19], (const float*)d_in[20],
        (const float*)d_in[21], (float*)d_out);
}